// Round 1
// baseline (530.126 us; speedup 1.0000x reference)
//
#include <hip/hip_runtime.h>
#include <cstdint>
#include <cstddef>

// Problem constants (B=2, S=2048, HID=1024, H=16, KVH=4, D=64)
#define S_LEN   2048
#define BATCH   2
#define HID_DIM 1024
#define NHEAD   16
#define NKV     4
#define DHEAD   64
#define SCALE_F 0.125f
#define CAP_F   50.0f

typedef unsigned short u16;
typedef __attribute__((ext_vector_type(8))) short  short8_t;  // 8 bf16 (4 VGPRs)
typedef __attribute__((ext_vector_type(4))) float  f32x4;
typedef __attribute__((ext_vector_type(4))) u16    u16x4;

static __device__ __forceinline__ u16 f2bf(float f) {
  uint32_t x = __builtin_bit_cast(uint32_t, f);
  x += 0x7fffu + ((x >> 16) & 1u);          // round-to-nearest-even
  return (u16)(x >> 16);
}
static __device__ __forceinline__ float bf2f(u16 u) {
  return __builtin_bit_cast(float, (uint32_t)u << 16);
}

// ---------------------------------------------------------------- cast fp32 -> bf16
__global__ void cast_bf16(const float* __restrict__ in, u16* __restrict__ out, int n4) {
  int i = blockIdx.x * 256 + threadIdx.x;
  if (i >= n4) return;
  f32x4 v = ((const f32x4*)in)[i];
  u16x4 o;
  o[0] = f2bf(v[0]); o[1] = f2bf(v[1]); o[2] = f2bf(v[2]); o[3] = f2bf(v[3]);
  ((u16x4*)out)[i] = o;
}

// ---------------------------------------------------------------- RoPE (in-place on bf16 buffer)
// buf layout: (BATCH*S, nh*64) row-major. cos/sin: (BATCH*S, 64) fp32.
__global__ void rope_kernel(u16* __restrict__ buf, const float* __restrict__ cosb,
                            const float* __restrict__ sinb, int nh, int total) {
  int idx = blockIdx.x * 256 + threadIdx.x;
  if (idx >= total) return;
  int d  = idx & 31;
  int t  = idx >> 5;
  int hh = t % nh;
  int n  = t / nh;
  size_t base = (size_t)n * (nh * 64) + hh * 64 + d;
  float x1 = bf2f(buf[base]);
  float x2 = bf2f(buf[base + 32]);
  int ci = n * 64 + d;
  float c1 = cosb[ci],      s1 = sinb[ci];
  float c2 = cosb[ci + 32], s2 = sinb[ci + 32];
  buf[base]      = f2bf(x1 * c1 - x2 * s1);
  buf[base + 32] = f2bf(x2 * c2 + x1 * s2);
}

// ---------------------------------------------------------------- GEMM: out = A(MxK) @ W(NxK)^T + bias
// bf16 inputs, fp32 accumulate. Per-wave 16x64 output, block = 4 waves = 64x64 tile.
template<int OUT_F32>
__global__ __launch_bounds__(256) void gemm_bt(const u16* __restrict__ A,
                                               const u16* __restrict__ W,
                                               const float* __restrict__ bias,
                                               void* __restrict__ outp,
                                               int M, int N, int K) {
  (void)M;
  const int lane = threadIdx.x & 63, w = threadIdx.x >> 6;
  const int l15 = lane & 15, lg = lane >> 4;
  const int m0 = blockIdx.x * 64 + w * 16;
  const int n0 = blockIdx.y * 64;

  const u16* arow  = A + (size_t)(m0 + l15) * K + lg * 8;
  const u16* wrow0 = W + (size_t)(n0 + l15) * K + lg * 8;

  f32x4 acc[4];
  #pragma unroll
  for (int j = 0; j < 4; ++j) acc[j] = (f32x4){0.f, 0.f, 0.f, 0.f};

  for (int kk = 0; kk < K; kk += 32) {
    short8_t a = *(const short8_t*)(arow + kk);
    #pragma unroll
    for (int j = 0; j < 4; ++j) {
      short8_t b = *(const short8_t*)(wrow0 + (size_t)j * 16 * K + kk);
      acc[j] = __builtin_amdgcn_mfma_f32_16x16x32_bf16(a, b, acc[j], 0, 0, 0);
    }
  }
  #pragma unroll
  for (int j = 0; j < 4; ++j) {
    const int col = n0 + j * 16 + l15;
    const float bv = bias[col];
    #pragma unroll
    for (int i = 0; i < 4; ++i) {
      const int row = m0 + lg * 4 + i;
      float v = acc[j][i] + bv;
      if (OUT_F32) ((float*)outp)[(size_t)row * N + col] = v;
      else         ((u16*)outp)[(size_t)row * N + col]   = f2bf(v);
    }
  }
}

// ---------------------------------------------------------------- fused causal attention
// grid: (S/64, B*H); block 256 (4 waves, 16 q-rows each).
// Pass 1: QK^T -> l = sum exp(s-50) (fixed max = CAP, valid since scores clipped to +-50).
// Pass 2: recompute scores, write attn = exp(s-50)/l (fp32) to d_out, accumulate PV via MFMA.
__global__ __launch_bounds__(256) void attn_fused(const u16* __restrict__ qb,
                                                  const u16* __restrict__ kb,
                                                  const u16* __restrict__ vb,
                                                  float* __restrict__ attn,
                                                  u16* __restrict__ ctxb) {
  __shared__ u16 pShm[4][16 * 32];   // per-wave P tile [16 q][32 kv]
  __shared__ u16 vtShm[64][40];      // V^T tile [d][kv], rows padded to 40 (80B, 16B-aligned)

  const int tid = threadIdx.x, lane = tid & 63, wid = tid >> 6;
  const int l15 = lane & 15, lg = lane >> 4;
  const int q0 = blockIdx.x * 64;
  const int bh = blockIdx.y, b = bh >> 4, h = bh & 15, kvh = h >> 2;
  const int qw = q0 + wid * 16;

  // Q fragments (held in registers across both passes)
  const u16* qp = qb + (size_t)(b * S_LEN + qw + l15) * HID_DIM + h * DHEAD + lg * 8;
  const short8_t a0 = *(const short8_t*)qp;
  const short8_t a1 = *(const short8_t*)(qp + 32);

  const u16* kbase = kb + (size_t)(b * S_LEN) * (NKV * DHEAD) + kvh * DHEAD + lg * 8;

  // ---- pass 1: row sums of exp(s - 50)
  float lsum[4] = {0.f, 0.f, 0.f, 0.f};
  const int Tw = qw / 16 + 1;
  for (int t = 0; t < Tw; ++t) {
    const u16* kp = kbase + (size_t)(t * 16 + l15) * (NKV * DHEAD);
    short8_t b0 = *(const short8_t*)kp;
    short8_t b1 = *(const short8_t*)(kp + 32);
    f32x4 sacc = (f32x4){0.f, 0.f, 0.f, 0.f};
    sacc = __builtin_amdgcn_mfma_f32_16x16x32_bf16(a0, b0, sacc, 0, 0, 0);
    sacc = __builtin_amdgcn_mfma_f32_16x16x32_bf16(a1, b1, sacc, 0, 0, 0);
    const int col = t * 16 + l15;
    #pragma unroll
    for (int i = 0; i < 4; ++i) {
      const int row = qw + lg * 4 + i;
      float sv = fminf(fmaxf(sacc[i] * SCALE_F, -CAP_F), CAP_F);
      sv = (col <= row) ? sv : -1e9f;
      lsum[i] += __expf(sv - CAP_F);
    }
  }
  float invl[4];
  #pragma unroll
  for (int i = 0; i < 4; ++i) {
    float v = lsum[i];
    v += __shfl_xor(v, 1, 16);
    v += __shfl_xor(v, 2, 16);
    v += __shfl_xor(v, 4, 16);
    v += __shfl_xor(v, 8, 16);
    invl[i] = 1.f / v;
  }

  // ---- pass 2: attn write + PV
  float* attnbase = attn + (size_t)bh * S_LEN * S_LEN;
  f32x4 ctx[4];
  #pragma unroll
  for (int dt = 0; dt < 4; ++dt) ctx[dt] = (f32x4){0.f, 0.f, 0.f, 0.f};

  const int T32 = (q0 + 64) / 32;
  for (int t32 = 0; t32 < T32; ++t32) {
    const int kv0 = t32 * 32;
    __syncthreads();
    { // stage V^T tile cooperatively: 32 kv rows x 64 d
      const int kv = tid >> 3, d0 = (tid & 7) * 8;
      short8_t vv = *(const short8_t*)(vb + (size_t)(b * S_LEN + kv0 + kv) * (NKV * DHEAD)
                                       + kvh * DHEAD + d0);
      #pragma unroll
      for (int j = 0; j < 8; ++j) vtShm[d0 + j][kv] = (u16)vv[j];
    }
    __syncthreads();

    #pragma unroll
    for (int half = 0; half < 2; ++half) {
      const int c0 = kv0 + half * 16;
      const u16* kp = kbase + (size_t)(c0 + l15) * (NKV * DHEAD);
      short8_t b0 = *(const short8_t*)kp;
      short8_t b1 = *(const short8_t*)(kp + 32);
      f32x4 sacc = (f32x4){0.f, 0.f, 0.f, 0.f};
      sacc = __builtin_amdgcn_mfma_f32_16x16x32_bf16(a0, b0, sacc, 0, 0, 0);
      sacc = __builtin_amdgcn_mfma_f32_16x16x32_bf16(a1, b1, sacc, 0, 0, 0);
      const int col = c0 + l15;
      #pragma unroll
      for (int i = 0; i < 4; ++i) {
        const int row = qw + lg * 4 + i;
        float sv = fminf(fmaxf(sacc[i] * SCALE_F, -CAP_F), CAP_F);
        sv = (col <= row) ? sv : -1e9f;
        float p = __expf(sv - CAP_F) * invl[i];
        attnbase[(size_t)row * S_LEN + col] = p;
        pShm[wid][(lg * 4 + i) * 32 + half * 16 + l15] = f2bf(p);
      }
    }
    // PV: A = P (from pShm, row=l15, k=lg*8+j), B = V (from vtShm[d][kv])
    short8_t pa = *(const short8_t*)&pShm[wid][l15 * 32 + lg * 8];
    #pragma unroll
    for (int dt = 0; dt < 4; ++dt) {
      short8_t bv = *(const short8_t*)&vtShm[dt * 16 + l15][lg * 8];
      ctx[dt] = __builtin_amdgcn_mfma_f32_16x16x32_bf16(pa, bv, ctx[dt], 0, 0, 0);
    }
  }

  // ctx -> bf16 ws buffer (B*S, HID) layout
  #pragma unroll
  for (int dt = 0; dt < 4; ++dt)
    #pragma unroll
    for (int i = 0; i < 4; ++i) {
      const int row = qw + lg * 4 + i;
      const int d = dt * 16 + l15;
      ctxb[(size_t)(b * S_LEN + row) * HID_DIM + h * DHEAD + d] = f2bf(ctx[dt][i]);
    }

  // zero-fill attn cols [q0+64, S) for this block's 64 rows (d_out is poisoned)
  const int zc0 = q0 + 64;
  if (zc0 < S_LEN) {
    const f32x4 z = (f32x4){0.f, 0.f, 0.f, 0.f};
    for (int r = wid; r < 64; r += 4) {
      float* rowp = attnbase + (size_t)(q0 + r) * S_LEN;
      for (int c = zc0 + lane * 4; c < S_LEN; c += 256)
        *(f32x4*)(rowp + c) = z;
    }
  }
}

// ---------------------------------------------------------------- launch
extern "C" void kernel_launch(void* const* d_in, const int* in_sizes, int n_in,
                              void* d_out, int out_size, void* d_ws, size_t ws_size,
                              hipStream_t stream) {
  (void)in_sizes; (void)n_in; (void)out_size; (void)ws_size;
  const float* X    = (const float*)d_in[0];
  const float* cosb = (const float*)d_in[1];
  const float* sinb = (const float*)d_in[2];
  // d_in[3] = mask (tril) -- causality applied analytically
  const float* Wq = (const float*)d_in[4];
  const float* bq = (const float*)d_in[5];
  const float* Wk = (const float*)d_in[6];
  const float* bk = (const float*)d_in[7];
  const float* Wv = (const float*)d_in[8];
  const float* bv = (const float*)d_in[9];
  const float* Wo = (const float*)d_in[10];
  const float* bo = (const float*)d_in[11];

  float* outp  = (float*)d_out;
  float* attnp = outp + (size_t)BATCH * S_LEN * HID_DIM;

  const int M = BATCH * S_LEN;           // 4096
  u16* ws   = (u16*)d_ws;
  u16* Xb   = ws;                        // 4096*1024
  u16* Wqb  = Xb  + (size_t)M * HID_DIM;           // 1024*1024
  u16* Wkb  = Wqb + (size_t)HID_DIM * HID_DIM;     // 256*1024
  u16* Wvb  = Wkb + (size_t)NKV * DHEAD * HID_DIM;
  u16* Wob  = Wvb + (size_t)NKV * DHEAD * HID_DIM; // 1024*1024
  u16* qbuf = Wob + (size_t)HID_DIM * HID_DIM;     // 4096*1024
  u16* kbuf = qbuf + (size_t)M * HID_DIM;          // 4096*256
  u16* vbuf = kbuf + (size_t)M * NKV * DHEAD;
  u16* ctxb = vbuf + (size_t)M * NKV * DHEAD;      // 4096*1024

  auto cast = [&](const float* src, u16* dst, int n) {
    int n4 = n / 4;
    cast_bf16<<<(n4 + 255) / 256, 256, 0, stream>>>(src, dst, n4);
  };
  cast(X,  Xb,  M * HID_DIM);
  cast(Wq, Wqb, HID_DIM * HID_DIM);
  cast(Wk, Wkb, NKV * DHEAD * HID_DIM);
  cast(Wv, Wvb, NKV * DHEAD * HID_DIM);
  cast(Wo, Wob, HID_DIM * HID_DIM);

  // projections (bf16 out)
  gemm_bt<0><<<dim3(M / 64, HID_DIM / 64), 256, 0, stream>>>(Xb, Wqb, bq, qbuf, M, HID_DIM, HID_DIM);
  gemm_bt<0><<<dim3(M / 64, (NKV * DHEAD) / 64), 256, 0, stream>>>(Xb, Wkb, bk, kbuf, M, NKV * DHEAD, HID_DIM);
  gemm_bt<0><<<dim3(M / 64, (NKV * DHEAD) / 64), 256, 0, stream>>>(Xb, Wvb, bv, vbuf, M, NKV * DHEAD, HID_DIM);

  // RoPE on q and k
  rope_kernel<<<(M * NHEAD * 32) / 256, 256, 0, stream>>>(qbuf, cosb, sinb, NHEAD, M * NHEAD * 32);
  rope_kernel<<<(M * NKV * 32) / 256, 256, 0, stream>>>(kbuf, cosb, sinb, NKV, M * NKV * 32);

  // fused attention: writes attn (fp32) + ctx (bf16)
  attn_fused<<<dim3(S_LEN / 64, BATCH * NHEAD), 256, 0, stream>>>(qbuf, kbuf, vbuf, attnp, ctxb);

  // output projection (fp32 out)
  gemm_bt<1><<<dim3(M / 64, HID_DIM / 64), 256, 0, stream>>>(ctxb, Wob, bo, outp, M, HID_DIM, HID_DIM);
}

// Round 2
// 327.193 us; speedup vs baseline: 1.6202x; 1.6202x over previous
//
#include <hip/hip_runtime.h>
#include <cstdint>
#include <cstddef>

// Problem constants (B=2, S=2048, HID=1024, H=16, KVH=4, D=64)
#define S_LEN   2048
#define BATCH   2
#define HID_DIM 1024
#define NHEAD   16
#define NKV     4
#define DHEAD   64
#define SCALE_F 0.125f
#define CAP_F   50.0f

typedef unsigned short u16;
typedef __attribute__((ext_vector_type(8))) short  short8_t;  // 8 bf16
typedef __attribute__((ext_vector_type(4))) float  f32x4;
typedef __attribute__((ext_vector_type(4))) u16    u16x4;

static __device__ __forceinline__ u16 f2bf(float f) {
  uint32_t x = __builtin_bit_cast(uint32_t, f);
  x += 0x7fffu + ((x >> 16) & 1u);
  return (u16)(x >> 16);
}
static __device__ __forceinline__ float bf2f(u16 u) {
  return __builtin_bit_cast(float, (uint32_t)u << 16);
}

static __device__ __forceinline__ void gload_lds16(const void* g, void* l) {
  __builtin_amdgcn_global_load_lds((const __attribute__((address_space(1))) void*)g,
                                   (__attribute__((address_space(3))) void*)l, 16, 0, 0);
}

// ---------------------------------------------------------------- cast fp32 -> bf16
__global__ void cast_bf16(const float* __restrict__ in, u16* __restrict__ out, int n4) {
  int i = blockIdx.x * 256 + threadIdx.x;
  if (i >= n4) return;
  f32x4 v = ((const f32x4*)in)[i];
  u16x4 o;
  o[0] = f2bf(v[0]); o[1] = f2bf(v[1]); o[2] = f2bf(v[2]); o[3] = f2bf(v[3]);
  ((u16x4*)out)[i] = o;
}

// ---------------------------------------------------------------- RoPE (in-place)
__global__ void rope_kernel(u16* __restrict__ buf, const float* __restrict__ cosb,
                            const float* __restrict__ sinb, int nh, int total) {
  int idx = blockIdx.x * 256 + threadIdx.x;
  if (idx >= total) return;
  int d  = idx & 31;
  int t  = idx >> 5;
  int hh = t % nh;
  int n  = t / nh;
  size_t base = (size_t)n * (nh * 64) + hh * 64 + d;
  float x1 = bf2f(buf[base]);
  float x2 = bf2f(buf[base + 32]);
  int ci = n * 64 + d;
  float c1 = cosb[ci],      s1 = sinb[ci];
  float c2 = cosb[ci + 32], s2 = sinb[ci + 32];
  buf[base]      = f2bf(x1 * c1 - x2 * s1);
  buf[base + 32] = f2bf(x2 * c2 + x1 * s2);
}

// ---------------------------------------------------------------- GEMM (m97 structure)
// out[M][N] = A[M][K] @ W[N][K]^T + bias.  BM=BN=128, BK=64, 256 thr (2x2 waves, 64x64/wave).
// Swapped MFMA (A-op = W rows, B-op = X rows) -> lane holds 4 consecutive N elems -> f32x4 stores.
// LDS: linear rows of 128B, 16B-granule XOR-swizzled by (row&7); staged via global_load_lds
// with pre-swizzled global source (T2 + guide rule 21).
template<int OUT_F32>
__global__ __launch_bounds__(256) void gemm_bt(const u16* __restrict__ A,
                                               const u16* __restrict__ W,
                                               const float* __restrict__ bias,
                                               void* __restrict__ outp,
                                               int M, int N, int K) {
  (void)M;
  __shared__ u16 As[128 * 64];
  __shared__ u16 Bs[128 * 64];
  const int tid = threadIdx.x, lane = tid & 63, wid = tid >> 6;
  const int l15 = lane & 15, lg = lane >> 4;
  const int m0 = blockIdx.x * 128, n0 = blockIdx.y * 128;
  const int wm = wid & 1, wn = wid >> 1;   // wave block: rows m0+wm*64, cols n0+wn*64

  f32x4 acc[4][4];   // [fn][fm]
  #pragma unroll
  for (int a = 0; a < 4; ++a)
    #pragma unroll
    for (int b2 = 0; b2 < 4; ++b2) acc[a][b2] = (f32x4){0.f, 0.f, 0.f, 0.f};

  // staging geometry: chunk c covers tile rows c*8..c*8+7 (1KB); lane l -> row c*8+(l>>3),
  // LDS granule (l&7); global granule = (l&7) ^ (row&7)  (inverse swizzle at source)
  const int srow = (lane >> 3), sg = (lane & 7);

  for (int kk = 0; kk < K; kk += 64) {
    __syncthreads();
    #pragma unroll
    for (int i = 0; i < 4; ++i) {
      const int c = wid * 4 + i;
      const int r = c * 8 + srow;
      const int g = sg ^ (r & 7);
      gload_lds16(A + (size_t)(m0 + r) * K + kk + g * 8, As + c * 512);
      gload_lds16(W + (size_t)(n0 + r) * K + kk + g * 8, Bs + c * 512);
    }
    __syncthreads();
    #pragma unroll
    for (int ks = 0; ks < 2; ++ks) {
      short8_t xa[4], wb[4];
      #pragma unroll
      for (int f = 0; f < 4; ++f) {
        const int rm = wm * 64 + f * 16 + l15;
        const int rn = wn * 64 + f * 16 + l15;
        xa[f] = *(const short8_t*)(As + rm * 64 + (((ks * 4 + lg) ^ (rm & 7)) * 8));
        wb[f] = *(const short8_t*)(Bs + rn * 64 + (((ks * 4 + lg) ^ (rn & 7)) * 8));
      }
      #pragma unroll
      for (int fn = 0; fn < 4; ++fn)
        #pragma unroll
        for (int fm = 0; fm < 4; ++fm)
          acc[fn][fm] = __builtin_amdgcn_mfma_f32_16x16x32_bf16(wb[fn], xa[fm], acc[fn][fm], 0, 0, 0);
    }
  }

  const int m_base = m0 + wm * 64, n_base = n0 + wn * 64;
  #pragma unroll
  for (int fn = 0; fn < 4; ++fn) {
    const int col = n_base + fn * 16 + lg * 4;
    const f32x4 bv = *(const f32x4*)(bias + col);
    #pragma unroll
    for (int fm = 0; fm < 4; ++fm) {
      const int row = m_base + fm * 16 + l15;
      f32x4 v = acc[fn][fm] + bv;
      if (OUT_F32) {
        *(f32x4*)((float*)outp + (size_t)row * N + col) = v;
      } else {
        u16x4 o;
        o[0] = f2bf(v[0]); o[1] = f2bf(v[1]); o[2] = f2bf(v[2]); o[3] = f2bf(v[3]);
        *(u16x4*)((u16*)outp + (size_t)row * N + col) = o;
      }
    }
  }
}

// ---------------------------------------------------------------- fused causal attention
// grid (S/64, B*H), 256 thr (4 waves x 16 q-rows). Swapped QK^T: mfma(K,Q) -> lane owns
// q-row = qw+l15, kv cols = c0+lg*4+i  => f32x4 attn stores, per-lane row-sums.
// Fixed softmax max = CAP (scores clipped to +-50). K staged in swizzled LDS per 32-chunk.
__global__ __launch_bounds__(256) void attn_fused(const u16* __restrict__ qb,
                                                  const u16* __restrict__ kb,
                                                  const u16* __restrict__ vb,
                                                  float* __restrict__ attn,
                                                  u16* __restrict__ ctxb) {
  __shared__ u16 kShm[32 * 64];      // K chunk, granule-XOR-swizzled, 128B rows
  __shared__ u16 vtShm[64][72];      // V^T chunk [d][kv], 144B rows (16B aligned, bank-spread)
  __shared__ u16 pShm[4][16][40];    // per-wave P tile [q][kv], 80B rows

  const int tid = threadIdx.x, lane = tid & 63, wid = tid >> 6;
  const int l15 = lane & 15, lg = lane >> 4;
  const int q0 = blockIdx.x * 64;
  const int bh = blockIdx.y, b = bh >> 4, h = bh & 15, kvh = h >> 2;
  const int qw = q0 + wid * 16;
  const int qrow = qw + l15;

  // Q fragment (B-operand): col = q = l15-row, k = d
  const u16* qp = qb + (size_t)(b * S_LEN + qrow) * HID_DIM + h * DHEAD + lg * 8;
  const short8_t qf0 = *(const short8_t*)qp;
  const short8_t qf1 = *(const short8_t*)(qp + 32);

  const u16* kvbase = kb + (size_t)(b * S_LEN) * (NKV * DHEAD) + kvh * DHEAD;
  const u16* vbase  = vb + (size_t)(b * S_LEN) * (NKV * DHEAD) + kvh * DHEAD;

  // staging lane geometry
  const int skv = tid >> 3, sc = tid & 7;            // K: row skv, granule sc
  const int vkv = tid & 31, vd0 = (tid >> 5) * 8;    // V: row vkv, d-cols vd0..vd0+7

  const int T32 = (q0 + 64) / 32;

  // ---------------- pass 1: row sums of exp(s - CAP)
  float lsum = 0.f;
  for (int t32 = 0; t32 < T32; ++t32) {
    const int kv0 = t32 * 32;
    __syncthreads();
    { // stage K chunk (32 rows x 64), swizzled granules
      short8_t kv = *(const short8_t*)(kvbase + (size_t)(kv0 + skv) * (NKV * DHEAD) + sc * 8);
      *(short8_t*)(kShm + skv * 64 + ((sc ^ (skv & 7)) * 8)) = kv;
    }
    __syncthreads();
    #pragma unroll
    for (int half = 0; half < 2; ++half) {
      const int row = half * 16 + l15;
      short8_t ka = *(const short8_t*)(kShm + row * 64 + ((lg ^ (row & 7)) * 8));
      short8_t kb2 = *(const short8_t*)(kShm + row * 64 + (((4 + lg) ^ (row & 7)) * 8));
      f32x4 sacc = (f32x4){0.f, 0.f, 0.f, 0.f};
      sacc = __builtin_amdgcn_mfma_f32_16x16x32_bf16(ka, qf0, sacc, 0, 0, 0);
      sacc = __builtin_amdgcn_mfma_f32_16x16x32_bf16(kb2, qf1, sacc, 0, 0, 0);
      #pragma unroll
      for (int i = 0; i < 4; ++i) {
        const int kvi = kv0 + half * 16 + lg * 4 + i;
        float sv = fminf(fmaxf(sacc[i] * SCALE_F, -CAP_F), CAP_F);
        lsum += (kvi <= qrow) ? __expf(sv - CAP_F) : 0.f;
      }
    }
  }
  lsum += __shfl_xor(lsum, 16);
  lsum += __shfl_xor(lsum, 32);
  const float invl = 1.f / lsum;

  // ---------------- pass 2: attn write + PV
  float* attnbase = attn + (size_t)bh * S_LEN * S_LEN;
  f32x4 ctx[4];
  #pragma unroll
  for (int dt = 0; dt < 4; ++dt) ctx[dt] = (f32x4){0.f, 0.f, 0.f, 0.f};

  for (int t32 = 0; t32 < T32; ++t32) {
    const int kv0 = t32 * 32;
    __syncthreads();
    { // stage K (swizzled) + V^T
      short8_t kv = *(const short8_t*)(kvbase + (size_t)(kv0 + skv) * (NKV * DHEAD) + sc * 8);
      *(short8_t*)(kShm + skv * 64 + ((sc ^ (skv & 7)) * 8)) = kv;
      short8_t vv = *(const short8_t*)(vbase + (size_t)(kv0 + vkv) * (NKV * DHEAD) + vd0);
      #pragma unroll
      for (int j = 0; j < 8; ++j) vtShm[vd0 + j][vkv] = (u16)vv[j];
    }
    __syncthreads();
    #pragma unroll
    for (int half = 0; half < 2; ++half) {
      const int c0 = kv0 + half * 16;
      const int row = half * 16 + l15;
      short8_t ka = *(const short8_t*)(kShm + row * 64 + ((lg ^ (row & 7)) * 8));
      short8_t kb2 = *(const short8_t*)(kShm + row * 64 + (((4 + lg) ^ (row & 7)) * 8));
      f32x4 sacc = (f32x4){0.f, 0.f, 0.f, 0.f};
      sacc = __builtin_amdgcn_mfma_f32_16x16x32_bf16(ka, qf0, sacc, 0, 0, 0);
      sacc = __builtin_amdgcn_mfma_f32_16x16x32_bf16(kb2, qf1, sacc, 0, 0, 0);
      f32x4 pv;
      u16x4 pb;
      #pragma unroll
      for (int i = 0; i < 4; ++i) {
        const int kvi = c0 + lg * 4 + i;
        float sv = fminf(fmaxf(sacc[i] * SCALE_F, -CAP_F), CAP_F);
        float p = (kvi <= qrow) ? __expf(sv - CAP_F) * invl : 0.f;
        pv[i] = p;
        pb[i] = f2bf(p);
      }
      *(f32x4*)(attnbase + (size_t)qrow * S_LEN + c0 + lg * 4) = pv;
      *(u16x4*)&pShm[wid][l15][half * 16 + lg * 4] = pb;
    }
    // PV: A = P[q=l15][k=lg*8+j], B = V[k][d=dt*16+l15]
    short8_t pa = *(const short8_t*)&pShm[wid][l15][lg * 8];
    #pragma unroll
    for (int dt = 0; dt < 4; ++dt) {
      short8_t bvv = *(const short8_t*)&vtShm[dt * 16 + l15][lg * 8];
      ctx[dt] = __builtin_amdgcn_mfma_f32_16x16x32_bf16(pa, bvv, ctx[dt], 0, 0, 0);
    }
  }

  // ctx -> bf16 (B*S, HID): C layout: row q = qw+lg*4+i, col d = dt*16+l15
  #pragma unroll
  for (int dt = 0; dt < 4; ++dt)
    #pragma unroll
    for (int i = 0; i < 4; ++i) {
      const int row = qw + lg * 4 + i;
      const int d = dt * 16 + l15;
      ctxb[(size_t)(b * S_LEN + row) * HID_DIM + h * DHEAD + d] = f2bf(ctx[dt][i]);
    }

  // zero-fill attn cols [q0+64, S)
  const int zc0 = q0 + 64;
  if (zc0 < S_LEN) {
    const f32x4 z = (f32x4){0.f, 0.f, 0.f, 0.f};
    for (int r = wid; r < 64; r += 4) {
      float* rowp = attnbase + (size_t)(q0 + r) * S_LEN;
      for (int c = zc0 + lane * 4; c < S_LEN; c += 256)
        *(f32x4*)(rowp + c) = z;
    }
  }
}

// ---------------------------------------------------------------- launch
extern "C" void kernel_launch(void* const* d_in, const int* in_sizes, int n_in,
                              void* d_out, int out_size, void* d_ws, size_t ws_size,
                              hipStream_t stream) {
  (void)in_sizes; (void)n_in; (void)out_size; (void)ws_size;
  const float* X    = (const float*)d_in[0];
  const float* cosb = (const float*)d_in[1];
  const float* sinb = (const float*)d_in[2];
  const float* Wq = (const float*)d_in[4];
  const float* bq = (const float*)d_in[5];
  const float* Wk = (const float*)d_in[6];
  const float* bk = (const float*)d_in[7];
  const float* Wv = (const float*)d_in[8];
  const float* bv = (const float*)d_in[9];
  const float* Wo = (const float*)d_in[10];
  const float* bo = (const float*)d_in[11];

  float* outp  = (float*)d_out;
  float* attnp = outp + (size_t)BATCH * S_LEN * HID_DIM;

  const int M = BATCH * S_LEN;           // 4096
  u16* ws   = (u16*)d_ws;
  u16* Xb   = ws;
  u16* Wqb  = Xb  + (size_t)M * HID_DIM;
  u16* Wkb  = Wqb + (size_t)HID_DIM * HID_DIM;
  u16* Wvb  = Wkb + (size_t)NKV * DHEAD * HID_DIM;
  u16* Wob  = Wvb + (size_t)NKV * DHEAD * HID_DIM;
  u16* qbuf = Wob + (size_t)HID_DIM * HID_DIM;
  u16* kbuf = qbuf + (size_t)M * HID_DIM;
  u16* vbuf = kbuf + (size_t)M * NKV * DHEAD;
  u16* ctxb = vbuf + (size_t)M * NKV * DHEAD;

  auto cast = [&](const float* src, u16* dst, int n) {
    int n4 = n / 4;
    cast_bf16<<<(n4 + 255) / 256, 256, 0, stream>>>(src, dst, n4);
  };
  cast(X,  Xb,  M * HID_DIM);
  cast(Wq, Wqb, HID_DIM * HID_DIM);
  cast(Wk, Wkb, NKV * DHEAD * HID_DIM);
  cast(Wv, Wvb, NKV * DHEAD * HID_DIM);
  cast(Wo, Wob, HID_DIM * HID_DIM);

  gemm_bt<0><<<dim3(M / 128, HID_DIM / 128), 256, 0, stream>>>(Xb, Wqb, bq, qbuf, M, HID_DIM, HID_DIM);
  gemm_bt<0><<<dim3(M / 128, (NKV * DHEAD) / 128), 256, 0, stream>>>(Xb, Wkb, bk, kbuf, M, NKV * DHEAD, HID_DIM);
  gemm_bt<0><<<dim3(M / 128, (NKV * DHEAD) / 128), 256, 0, stream>>>(Xb, Wvb, bv, vbuf, M, NKV * DHEAD, HID_DIM);

  rope_kernel<<<(M * NHEAD * 32) / 256, 256, 0, stream>>>(qbuf, cosb, sinb, NHEAD, M * NHEAD * 32);
  rope_kernel<<<(M * NKV * 32) / 256, 256, 0, stream>>>(kbuf, cosb, sinb, NKV, M * NKV * 32);

  attn_fused<<<dim3(S_LEN / 64, BATCH * NHEAD), 256, 0, stream>>>(qbuf, kbuf, vbuf, attnp, ctxb);

  gemm_bt<1><<<dim3(M / 128, HID_DIM / 128), 256, 0, stream>>>(ctxb, Wob, bo, outp, M, HID_DIM, HID_DIM);
}

// Round 3
// 223.213 us; speedup vs baseline: 2.3750x; 1.4658x over previous
//
#include <hip/hip_runtime.h>
#include <cstdint>
#include <cstddef>

// Problem constants (B=2, S=2048, HID=1024, H=16, KVH=4, D=64)
#define S_LEN   2048
#define BATCH   2
#define HID_DIM 1024
#define NHEAD   16
#define NKV     4
#define DHEAD   64
#define SCALE_F 0.125f
#define CAP_F   50.0f

typedef unsigned short u16;
typedef __attribute__((ext_vector_type(8))) short  short8_t;  // 8 bf16
typedef __attribute__((ext_vector_type(4))) float  f32x4;
typedef __attribute__((ext_vector_type(4))) u16    u16x4;

static __device__ __forceinline__ u16 f2bf(float f) {
  uint32_t x = __builtin_bit_cast(uint32_t, f);
  x += 0x7fffu + ((x >> 16) & 1u);
  return (u16)(x >> 16);
}

static __device__ __forceinline__ void gload_lds16(const void* g, void* l) {
  __builtin_amdgcn_global_load_lds((const __attribute__((address_space(1))) void*)g,
                                   (__attribute__((address_space(3))) void*)l, 16, 0, 0);
}

// ---------------------------------------------------------------- fused fp32->bf16 casts
__global__ void cast_all(const float* __restrict__ X,  u16* __restrict__ xb,
                         const float* __restrict__ Wq, u16* __restrict__ wqb,
                         const float* __restrict__ Wk, u16* __restrict__ wkb,
                         const float* __restrict__ Wv, u16* __restrict__ wvb,
                         const float* __restrict__ Wo, u16* __restrict__ wob) {
  const float* src; u16* dst; int n4;
  switch (blockIdx.y) {
    case 0:  src = X;  dst = xb;  n4 = (BATCH * S_LEN * HID_DIM) / 4; break;
    case 1:  src = Wq; dst = wqb; n4 = (HID_DIM * HID_DIM) / 4;       break;
    case 2:  src = Wk; dst = wkb; n4 = (NKV * DHEAD * HID_DIM) / 4;   break;
    case 3:  src = Wv; dst = wvb; n4 = (NKV * DHEAD * HID_DIM) / 4;   break;
    default: src = Wo; dst = wob; n4 = (HID_DIM * HID_DIM) / 4;       break;
  }
  for (int i = blockIdx.x * 256 + threadIdx.x; i < n4; i += gridDim.x * 256) {
    f32x4 v = ((const f32x4*)src)[i];
    u16x4 o;
    o[0] = f2bf(v[0]); o[1] = f2bf(v[1]); o[2] = f2bf(v[2]); o[3] = f2bf(v[3]);
    ((u16x4*)dst)[i] = o;
  }
}

// ---------------------------------------------------------------- fused QKV GEMM + RoPE + V-transpose
// out = X(Mx1024) @ [Wq;Wk;Wv](1536x1024)^T. BM=BN=128, BK=64, 4 waves.
// n0<1024 -> q (RoPE, bf16 row-major); 1024..1279 -> k (RoPE); >=1280 -> v (transposed [b][kvh][d][s]).
__global__ __launch_bounds__(256) void gemm_qkv(const u16* __restrict__ Xb,
                                                const u16* __restrict__ Wqb,
                                                const u16* __restrict__ Wkb,
                                                const u16* __restrict__ Wvb,
                                                const float* __restrict__ bq,
                                                const float* __restrict__ bk,
                                                const float* __restrict__ bv,
                                                const float* __restrict__ cosb,
                                                const float* __restrict__ sinb,
                                                u16* __restrict__ qout,
                                                u16* __restrict__ kout,
                                                u16* __restrict__ vtout) {
  __shared__ u16 As[128 * 64];
  __shared__ u16 Bs[128 * 64];
  const int tid = threadIdx.x, lane = tid & 63, wid = tid >> 6;
  const int l15 = lane & 15, lg = lane >> 4;
  const int m0 = blockIdx.x * 128, n0 = blockIdx.y * 128;
  const int wm = wid & 1, wn = wid >> 1;
  const int K = HID_DIM;

  const u16* Wp; const float* biasp; int nl, mode;
  if (n0 < 1024)      { Wp = Wqb; biasp = bq; nl = n0;        mode = 0; }
  else if (n0 < 1280) { Wp = Wkb; biasp = bk; nl = n0 - 1024; mode = 1; }
  else                { Wp = Wvb; biasp = bv; nl = n0 - 1280; mode = 2; }

  f32x4 acc[4][4];   // [fn][fm]
  #pragma unroll
  for (int a = 0; a < 4; ++a)
    #pragma unroll
    for (int b2 = 0; b2 < 4; ++b2) acc[a][b2] = (f32x4){0.f, 0.f, 0.f, 0.f};

  const int srow = (lane >> 3), sg = (lane & 7);

  for (int kk = 0; kk < K; kk += 64) {
    __syncthreads();
    #pragma unroll
    for (int i = 0; i < 4; ++i) {
      const int c = wid * 4 + i;
      const int r = c * 8 + srow;
      const int g = sg ^ (r & 7);
      gload_lds16(Xb + (size_t)(m0 + r) * K + kk + g * 8, As + c * 512);
      gload_lds16(Wp + (size_t)(nl + r) * K + kk + g * 8, Bs + c * 512);
    }
    __syncthreads();
    #pragma unroll
    for (int ks = 0; ks < 2; ++ks) {
      short8_t xa[4], wb[4];
      #pragma unroll
      for (int f = 0; f < 4; ++f) {
        const int rm = wm * 64 + f * 16 + l15;
        const int rn = wn * 64 + f * 16 + l15;
        xa[f] = *(const short8_t*)(As + rm * 64 + (((ks * 4 + lg) ^ (rm & 7)) * 8));
        wb[f] = *(const short8_t*)(Bs + rn * 64 + (((ks * 4 + lg) ^ (rn & 7)) * 8));
      }
      #pragma unroll
      for (int fn = 0; fn < 4; ++fn)
        #pragma unroll
        for (int fm = 0; fm < 4; ++fm)
          acc[fn][fm] = __builtin_amdgcn_mfma_f32_16x16x32_bf16(wb[fn], xa[fm], acc[fn][fm], 0, 0, 0);
    }
  }

  const int m_base = m0 + wm * 64;
  const int nlb = nl + wn * 64;          // local col base of this wave (multiple of 64)

  if (mode < 2) {
    // q/k: bias + RoPE (pairs are fragments fn and fn+2, same lane), vectorized bf16 store
    const int Nout = (mode == 0) ? HID_DIM : (NKV * DHEAD);
    u16* outb = (mode == 0) ? qout : kout;
    #pragma unroll
    for (int fm = 0; fm < 4; ++fm) {
      const int row = m_base + fm * 16 + l15;
      #pragma unroll
      for (int fn = 0; fn < 2; ++fn) {
        const int dh = fn * 16 + lg * 4;          // in [0,32)
        const f32x4 c4 = *(const f32x4*)(cosb + (size_t)row * 64 + dh);
        const f32x4 s4 = *(const f32x4*)(sinb + (size_t)row * 64 + dh);
        f32x4 x1 = acc[fn][fm]     + *(const f32x4*)(biasp + nlb + fn * 16 + lg * 4);
        f32x4 x2 = acc[fn + 2][fm] + *(const f32x4*)(biasp + nlb + (fn + 2) * 16 + lg * 4);
        f32x4 o1 = x1 * c4 - x2 * s4;
        f32x4 o2 = x2 * c4 + x1 * s4;
        u16x4 u1, u2;
        #pragma unroll
        for (int i = 0; i < 4; ++i) { u1[i] = f2bf(o1[i]); u2[i] = f2bf(o2[i]); }
        *(u16x4*)(outb + (size_t)row * Nout + nlb + fn * 16 + lg * 4)       = u1;
        *(u16x4*)(outb + (size_t)row * Nout + nlb + (fn + 2) * 16 + lg * 4) = u2;
      }
    }
  } else {
    // v: bias, store transposed vtout[(b*256 + col)*S + s]
    #pragma unroll
    for (int fn = 0; fn < 4; ++fn) {
      const int cb = nlb + fn * 16 + lg * 4;
      #pragma unroll
      for (int fm = 0; fm < 4; ++fm) {
        const int row = m_base + fm * 16 + l15;
        const int b_ = row >> 11, s_ = row & (S_LEN - 1);
        f32x4 v = acc[fn][fm];
        #pragma unroll
        for (int i = 0; i < 4; ++i) {
          vtout[(size_t)(b_ * 256 + cb + i) * S_LEN + s_] = f2bf(v[i] + biasp[cb + i]);
        }
      }
    }
  }
}

// ---------------------------------------------------------------- out-proj GEMM (fp32 out)
__global__ __launch_bounds__(256) void gemm_out(const u16* __restrict__ A,
                                                const u16* __restrict__ W,
                                                const float* __restrict__ bias,
                                                float* __restrict__ outp) {
  __shared__ u16 As[128 * 64];
  __shared__ u16 Bs[128 * 64];
  const int tid = threadIdx.x, lane = tid & 63, wid = tid >> 6;
  const int l15 = lane & 15, lg = lane >> 4;
  const int m0 = blockIdx.x * 128, n0 = blockIdx.y * 128;
  const int wm = wid & 1, wn = wid >> 1;
  const int K = HID_DIM, N = HID_DIM;

  f32x4 acc[4][4];
  #pragma unroll
  for (int a = 0; a < 4; ++a)
    #pragma unroll
    for (int b2 = 0; b2 < 4; ++b2) acc[a][b2] = (f32x4){0.f, 0.f, 0.f, 0.f};

  const int srow = (lane >> 3), sg = (lane & 7);

  for (int kk = 0; kk < K; kk += 64) {
    __syncthreads();
    #pragma unroll
    for (int i = 0; i < 4; ++i) {
      const int c = wid * 4 + i;
      const int r = c * 8 + srow;
      const int g = sg ^ (r & 7);
      gload_lds16(A + (size_t)(m0 + r) * K + kk + g * 8, As + c * 512);
      gload_lds16(W + (size_t)(n0 + r) * K + kk + g * 8, Bs + c * 512);
    }
    __syncthreads();
    #pragma unroll
    for (int ks = 0; ks < 2; ++ks) {
      short8_t xa[4], wb[4];
      #pragma unroll
      for (int f = 0; f < 4; ++f) {
        const int rm = wm * 64 + f * 16 + l15;
        const int rn = wn * 64 + f * 16 + l15;
        xa[f] = *(const short8_t*)(As + rm * 64 + (((ks * 4 + lg) ^ (rm & 7)) * 8));
        wb[f] = *(const short8_t*)(Bs + rn * 64 + (((ks * 4 + lg) ^ (rn & 7)) * 8));
      }
      #pragma unroll
      for (int fn = 0; fn < 4; ++fn)
        #pragma unroll
        for (int fm = 0; fm < 4; ++fm)
          acc[fn][fm] = __builtin_amdgcn_mfma_f32_16x16x32_bf16(wb[fn], xa[fm], acc[fn][fm], 0, 0, 0);
    }
  }

  const int m_base = m0 + wm * 64, n_base = n0 + wn * 64;
  #pragma unroll
  for (int fn = 0; fn < 4; ++fn) {
    const int col = n_base + fn * 16 + lg * 4;
    const f32x4 bvv = *(const f32x4*)(bias + col);
    #pragma unroll
    for (int fm = 0; fm < 4; ++fm) {
      const int row = m_base + fm * 16 + l15;
      *(f32x4*)(outp + (size_t)row * N + col) = acc[fn][fm] + bvv;
    }
  }
}

// ---------------------------------------------------------------- fused causal attention
// grid (B*H, S/64), 256 thr (4 waves x 16 q-rows). KVBLK=64, double-buffered K/V via
// global_load_lds + counted vmcnt + raw barriers. qt = gridDim.y-1-blockIdx.y (longest first).
__global__ __launch_bounds__(256) void attn_fused(const u16* __restrict__ qb,
                                                  const u16* __restrict__ kb,
                                                  const u16* __restrict__ vtb,
                                                  float* __restrict__ attn,
                                                  u16* __restrict__ ctxb) {
  __shared__ u16 kS[2][64 * 64];
  __shared__ u16 vS[2][64 * 64];
  __shared__ u16 pS[4][16][72];

  const int tid = threadIdx.x, lane = tid & 63, wid = tid >> 6;
  const int l15 = lane & 15, lg = lane >> 4;
  const int bh = blockIdx.x, b = bh >> 4, h = bh & 15, kvh = h >> 2;
  const int qt = (int)(gridDim.y - 1 - blockIdx.y);
  const int q0 = qt * 64;
  const int NT = qt + 1;
  const int qw = q0 + wid * 16;
  const int qrow = qw + l15;

  const u16* qp = qb + (size_t)(b * S_LEN + qrow) * HID_DIM + h * DHEAD + lg * 8;
  const short8_t qf0 = *(const short8_t*)qp;
  const short8_t qf1 = *(const short8_t*)(qp + 32);

  const u16* kbase  = kb  + (size_t)(b * S_LEN) * (NKV * DHEAD) + kvh * DHEAD;
  const u16* vtbase = vtb + (size_t)(b * NKV + kvh) * DHEAD * S_LEN;

  const int sr8 = wid * 8 + (lane >> 3);   // row within an issue-group, wave-partitioned
  const int sg  = lane & 7;

  auto stageK = [&](int bi, int kv0) {
    #pragma unroll
    for (int it = 0; it < 2; ++it) {
      const int r = it * 32 + sr8;
      const int g = sg ^ (r & 7);
      gload_lds16(kbase + (size_t)(kv0 + r) * (NKV * DHEAD) + g * 8,
                  &kS[bi][(it * 32 + wid * 8) * 64]);
    }
  };
  auto stageV = [&](int bi, int kv0) {
    #pragma unroll
    for (int it = 0; it < 2; ++it) {
      const int r = it * 32 + sr8;      // d row
      const int g = sg ^ (r & 7);
      gload_lds16(vtbase + (size_t)r * S_LEN + kv0 + g * 8,
                  &vS[bi][(it * 32 + wid * 8) * 64]);
    }
  };

  // ---------------- pass 1: lsum = sum exp(s - CAP) (fixed max: scores clipped to +-CAP)
  float lsum = 0.f;
  stageK(0, 0);
  for (int t = 0; t < NT; ++t) {
    const int kv0 = t * 64;
    if (t + 1 < NT) {
      stageK((t + 1) & 1, kv0 + 64);
      asm volatile("s_waitcnt vmcnt(2)" ::: "memory");
    } else {
      asm volatile("s_waitcnt vmcnt(0)" ::: "memory");
    }
    __builtin_amdgcn_s_barrier();
    const u16* ks = kS[t & 1];
    const bool maskc = (t == NT - 1);
    #pragma unroll
    for (int g16 = 0; g16 < 4; ++g16) {
      const int r = g16 * 16 + l15;
      short8_t ka0 = *(const short8_t*)(ks + r * 64 + ((lg ^ (r & 7)) * 8));
      short8_t ka1 = *(const short8_t*)(ks + r * 64 + (((4 + lg) ^ (r & 7)) * 8));
      f32x4 sacc = (f32x4){0.f, 0.f, 0.f, 0.f};
      sacc = __builtin_amdgcn_mfma_f32_16x16x32_bf16(ka0, qf0, sacc, 0, 0, 0);
      sacc = __builtin_amdgcn_mfma_f32_16x16x32_bf16(ka1, qf1, sacc, 0, 0, 0);
      #pragma unroll
      for (int i = 0; i < 4; ++i) {
        float sv = fminf(fmaxf(sacc[i] * SCALE_F, -CAP_F), CAP_F);
        float e = __expf(sv - CAP_F);
        if (maskc) {
          const int kvi = kv0 + g16 * 16 + lg * 4 + i;
          e = (kvi <= qrow) ? e : 0.f;
        }
        lsum += e;
      }
    }
    __builtin_amdgcn_s_barrier();
  }
  lsum += __shfl_xor(lsum, 16);
  lsum += __shfl_xor(lsum, 32);
  const float invl = 1.f / lsum;

  // ---------------- pass 2: attn write + PV
  float* abase = attn + (size_t)bh * S_LEN * S_LEN;
  float* arow  = abase + (size_t)qrow * S_LEN;
  f32x4 ctx[4];
  #pragma unroll
  for (int dt = 0; dt < 4; ++dt) ctx[dt] = (f32x4){0.f, 0.f, 0.f, 0.f};

  stageK(0, 0);
  stageV(0, 0);
  for (int t = 0; t < NT; ++t) {
    const int kv0 = t * 64;
    if (t + 1 < NT) {
      stageK((t + 1) & 1, kv0 + 64);
      stageV((t + 1) & 1, kv0 + 64);
      asm volatile("s_waitcnt vmcnt(4)" ::: "memory");
    } else {
      asm volatile("s_waitcnt vmcnt(0)" ::: "memory");
    }
    __builtin_amdgcn_s_barrier();
    const u16* ks = kS[t & 1];
    const u16* vs = vS[t & 1];
    const bool maskc = (t == NT - 1);
    #pragma unroll
    for (int g16 = 0; g16 < 4; ++g16) {
      const int r = g16 * 16 + l15;
      short8_t ka0 = *(const short8_t*)(ks + r * 64 + ((lg ^ (r & 7)) * 8));
      short8_t ka1 = *(const short8_t*)(ks + r * 64 + (((4 + lg) ^ (r & 7)) * 8));
      f32x4 sacc = (f32x4){0.f, 0.f, 0.f, 0.f};
      sacc = __builtin_amdgcn_mfma_f32_16x16x32_bf16(ka0, qf0, sacc, 0, 0, 0);
      sacc = __builtin_amdgcn_mfma_f32_16x16x32_bf16(ka1, qf1, sacc, 0, 0, 0);
      f32x4 pv; u16x4 pb;
      #pragma unroll
      for (int i = 0; i < 4; ++i) {
        float sv = fminf(fmaxf(sacc[i] * SCALE_F, -CAP_F), CAP_F);
        float e = __expf(sv - CAP_F);
        if (maskc) {
          const int kvi = kv0 + g16 * 16 + lg * 4 + i;
          e = (kvi <= qrow) ? e : 0.f;
        }
        float p = e * invl;
        pv[i] = p;
        pb[i] = f2bf(p);
      }
      *(f32x4*)(arow + kv0 + g16 * 16 + lg * 4) = pv;
      *(u16x4*)&pS[wid][l15][g16 * 16 + lg * 4] = pb;
    }
    short8_t pa0 = *(const short8_t*)&pS[wid][l15][lg * 8];
    short8_t pa1 = *(const short8_t*)&pS[wid][l15][32 + lg * 8];
    #pragma unroll
    for (int dt = 0; dt < 4; ++dt) {
      const int r = dt * 16 + l15;
      short8_t bv0 = *(const short8_t*)(vs + r * 64 + ((lg ^ (r & 7)) * 8));
      short8_t bv1 = *(const short8_t*)(vs + r * 64 + (((4 + lg) ^ (r & 7)) * 8));
      ctx[dt] = __builtin_amdgcn_mfma_f32_16x16x32_bf16(pa0, bv0, ctx[dt], 0, 0, 0);
      ctx[dt] = __builtin_amdgcn_mfma_f32_16x16x32_bf16(pa1, bv1, ctx[dt], 0, 0, 0);
    }
    __builtin_amdgcn_s_barrier();
  }

  // ctx -> bf16 ctxb: C layout row q = qw+lg*4+i, col d = dt*16+l15
  #pragma unroll
  for (int dt = 0; dt < 4; ++dt)
    #pragma unroll
    for (int i = 0; i < 4; ++i) {
      const int row = qw + lg * 4 + i;
      const int d = dt * 16 + l15;
      ctxb[(size_t)(b * S_LEN + row) * HID_DIM + h * DHEAD + d] = f2bf(ctx[dt][i]);
    }

  // zero-fill attn cols [q0+64, S)
  const int zc0 = q0 + 64;
  if (zc0 < S_LEN) {
    const f32x4 z = (f32x4){0.f, 0.f, 0.f, 0.f};
    for (int r = wid; r < 64; r += 4) {
      float* rowp = abase + (size_t)(q0 + r) * S_LEN;
      for (int c = zc0 + lane * 4; c < S_LEN; c += 256)
        *(f32x4*)(rowp + c) = z;
    }
  }
}

// ---------------------------------------------------------------- launch
extern "C" void kernel_launch(void* const* d_in, const int* in_sizes, int n_in,
                              void* d_out, int out_size, void* d_ws, size_t ws_size,
                              hipStream_t stream) {
  (void)in_sizes; (void)n_in; (void)out_size; (void)ws_size;
  const float* X    = (const float*)d_in[0];
  const float* cosb = (const float*)d_in[1];
  const float* sinb = (const float*)d_in[2];
  const float* Wq = (const float*)d_in[4];
  const float* bq = (const float*)d_in[5];
  const float* Wk = (const float*)d_in[6];
  const float* bk = (const float*)d_in[7];
  const float* Wv = (const float*)d_in[8];
  const float* bv = (const float*)d_in[9];
  const float* Wo = (const float*)d_in[10];
  const float* bo = (const float*)d_in[11];

  float* outp  = (float*)d_out;
  float* attnp = outp + (size_t)BATCH * S_LEN * HID_DIM;

  const int M = BATCH * S_LEN;           // 4096
  u16* ws    = (u16*)d_ws;
  u16* Xb    = ws;
  u16* Wqb   = Xb  + (size_t)M * HID_DIM;
  u16* Wkb   = Wqb + (size_t)HID_DIM * HID_DIM;
  u16* Wvb   = Wkb + (size_t)NKV * DHEAD * HID_DIM;
  u16* Wob   = Wvb + (size_t)NKV * DHEAD * HID_DIM;
  u16* qbuf  = Wob + (size_t)HID_DIM * HID_DIM;
  u16* kbuf  = qbuf + (size_t)M * HID_DIM;
  u16* vtbuf = kbuf + (size_t)M * NKV * DHEAD;     // [b][kvh][d][s] = (512, 2048)
  u16* ctxb  = vtbuf + (size_t)M * NKV * DHEAD;

  cast_all<<<dim3(1024, 5), 256, 0, stream>>>(X, Xb, Wq, Wqb, Wk, Wkb, Wv, Wvb, Wo, Wob);

  gemm_qkv<<<dim3(M / 128, 12), 256, 0, stream>>>(Xb, Wqb, Wkb, Wvb, bq, bk, bv,
                                                  cosb, sinb, qbuf, kbuf, vtbuf);

  attn_fused<<<dim3(BATCH * NHEAD, S_LEN / 64), 256, 0, stream>>>(qbuf, kbuf, vtbuf, attnp, ctxb);

  gemm_out<<<dim3(M / 128, HID_DIM / 128), 256, 0, stream>>>(ctxb, Wob, bo, outp);
}